// Round 4
// baseline (280.390 us; speedup 1.0000x reference)
//
#include <hip/hip_runtime.h>
#include <hip/hip_bf16.h>

// Problem: B=16, S=4096, H=1024
//   energy = tanh(x @ W^T + b); scores = softmax(energy, axis=S); out = sum_S scores*x
// GEMM view: M = B*S = 65536, N = H = 1024, K = H = 1024, both operands K-contiguous.
#define Bsz  16
#define Sdim 4096
#define Hdim 1024
#define Mtot (Bsz * Sdim)   // 65536
#define Kdim Hdim
#define Ndim Hdim

// ---- primary tile geometry (256^2, BK=32, 8 waves, 4-slot LDS ring) ----
#define BM2 256
#define BN2 256
#define BK2 32
#define MT2 (Mtot / BM2)    // 256
#define NT2 (Ndim / BN2)    // 4
#define NKT2 (Kdim / BK2)   // 32

// ---- fallback geometry (R1/R2-proven 128^2) ----
#define BM 128
#define BN 128
#define BK 32
#define MT (Mtot / BM)      // 512
#define NT (Ndim / BN)      // 8
#define NKT (Kdim / BK)     // 32

typedef short s16x8 __attribute__((ext_vector_type(8)));
typedef float f32x4 __attribute__((ext_vector_type(4)));

__device__ __forceinline__ unsigned short f2bf(float f) {
  __hip_bfloat16 h = __float2bfloat16(f);
  unsigned short u;
  __builtin_memcpy(&u, &h, 2);
  return u;
}
__device__ __forceinline__ float bf2f(unsigned short u) {
  __hip_bfloat16 h;
  __builtin_memcpy(&h, &u, 2);
  return __bfloat162float(h);
}
__device__ __forceinline__ s16x8 cvt8(float4 u, float4 v) {
  s16x8 r;
  r[0] = (short)f2bf(u.x); r[1] = (short)f2bf(u.y);
  r[2] = (short)f2bf(u.z); r[3] = (short)f2bf(u.w);
  r[4] = (short)f2bf(v.x); r[5] = (short)f2bf(v.y);
  r[6] = (short)f2bf(v.z); r[7] = (short)f2bf(v.w);
  return r;
}

// async global->LDS, 16B per lane; LDS dest is wave-uniform base + lane*16
__device__ __forceinline__ void gload_lds16(const unsigned short* g, unsigned short* l) {
  __builtin_amdgcn_global_load_lds(
      (const __attribute__((address_space(1))) unsigned int*)g,
      (__attribute__((address_space(3))) unsigned int*)l,
      16, 0, 0);
}

// ---- kernel 0: X fp32 [M][K] -> bf16 Xb (134 MB) ----
__global__ __launch_bounds__(256) void xconv_kernel(const float* __restrict__ X,
                                                    unsigned short* __restrict__ Xb) {
  size_t i = (size_t)blockIdx.x * 256 + threadIdx.x;  // 8 elements per thread
  float4 u = reinterpret_cast<const float4*>(X)[2 * i];
  float4 v = reinterpret_cast<const float4*>(X)[2 * i + 1];
  reinterpret_cast<s16x8*>(Xb)[i] = cvt8(u, v);
}

// ---- kernel 1: W fp32 [N][K] -> bf16 Wb (2 MB) ----
__global__ __launch_bounds__(256) void wconv_kernel(const float* __restrict__ W,
                                                    unsigned short* __restrict__ Wb) {
  int i = blockIdx.x * 256 + threadIdx.x;
  float4 v = reinterpret_cast<const float4*>(W)[i];
  ushort4 o;
  o.x = f2bf(v.x); o.y = f2bf(v.y); o.z = f2bf(v.z); o.w = f2bf(v.w);
  reinterpret_cast<ushort4*>(Wb)[i] = o;
}

// =====================================================================
// kernel 2 (primary): 256^2 GEMM, ONE barrier per K-tile, reads+MFMAs in
// the same barrier region (AITER-style ~32 MFMA per barrier).
//
// 512 threads = 8 waves (2 wm x 4 wn); per-wave output 128x64 = 8x4 frags
// of mfma_f32_16x16x32_bf16. LDS: 4-slot ring per operand (slot = 256x32
// bf16 = 16 KB), staging 3 tiles ahead, counted vmcnt (8 steady state).
//
// Per-iter safety invariants:
//  - tile t resident after barrier: each wave drained its OWN t-loads via
//    vmcnt(8) pre-barrier; barrier joins all waves.
//  - stage(t+3) overwrites slot (t-1)&3: every ds_read of tile t-1 was
//    consumed by an in-order MFMA before that wave could reach this
//    barrier, so no wave still reads slot (t-1)&3.
//
// T2 swizzle (R3-proven, 0 bank conflicts): phys_elem = row*32 +
// (col ^ (((row>>1)&3)<<3)); inverse applied to the per-lane GLOBAL
// source so the linear gload_lds dest lands data pre-swizzled.
// =====================================================================
__global__ __launch_bounds__(512, 2) void attn_main(
    const unsigned short* __restrict__ Xb,  // [Mtot][Kdim] bf16
    const unsigned short* __restrict__ Wb,  // [Ndim][Kdim] bf16
    const float* __restrict__ bias,         // [Ndim]
    float* __restrict__ lpart,              // [MT2][Ndim]
    float* __restrict__ cpart) {            // [MT2][Ndim]
  __shared__ unsigned short Asl[4][BM2 * BK2];  // 64 KB
  __shared__ unsigned short Bsl[4][BN2 * BK2];  // 64 KB
  __shared__ float red[2][2][BN2];              // 4 KB

  // XCD-chunked bijective swizzle (nwg=1024, 1024%8==0)
  int bid = blockIdx.x;
  int swz = (bid & 7) * (MT2 * NT2 / 8) + (bid >> 3);
  const int mt = swz >> 2;         // 0..255
  const int nt = swz & 3;          // 0..3
  const int m0 = mt * BM2;
  const int n0 = nt * BN2;

  const int tid  = threadIdx.x;
  const int l    = tid & 63;       // lane
  const int w    = tid >> 6;       // wave 0..7
  const int wm   = w >> 2;         // 0..1 (M half)
  const int wn   = w & 3;          // 0..3 (N quarter)
  const int lr   = l & 15;
  const int lk   = l >> 4;

  f32x4 acc[8][4];
#pragma unroll
  for (int i = 0; i < 8; i++)
#pragma unroll
    for (int j = 0; j < 4; j++) acc[i][j] = (f32x4){0.f, 0.f, 0.f, 0.f};

  // ---- staging source (inverse-swizzled global addresses) ----
  // One gload_lds unit = 512 thr x 16B = 8 KB = 128 rows. Wave w covers rows
  // [w*16, w*16+16) of the unit; lane: row += l>>2, src col elem =
  // ((l&3)^((l>>3)&3))*8  (pre-swizzle so linear LDS dest = swizzled layout).
  const int srow = w * 16 + (l >> 2);
  const int scol = (((l & 3) ^ ((l >> 3) & 3)) << 3);
  const unsigned short* srcA0 = Xb + (size_t)(m0 + srow) * Kdim + scol;
  const unsigned short* srcA1 = srcA0 + (size_t)128 * Kdim;
  const unsigned short* srcB0 = Wb + (size_t)(n0 + srow) * Kdim + scol;
  const unsigned short* srcB1 = srcB0 + (size_t)128 * Kdim;

  // ---- fragment read offsets (swizzled, lane-constant) ----
  int offA[8], offB[4];
#pragma unroll
  for (int mr = 0; mr < 8; mr++) {
    const int r = wm * 128 + mr * 16 + lr;
    offA[mr] = r * BK2 + ((lk * 8) ^ (((r >> 1) & 3) << 3));
  }
#pragma unroll
  for (int n = 0; n < 4; n++) {
    const int rn = wn * 64 + n * 16 + lr;
    offB[n] = rn * BK2 + ((lk * 8) ^ (((rn >> 1) & 3) << 3));
  }

  // ---- prologue: issue tiles 0,1,2 (12 gload_lds per wave) ----
#pragma unroll
  for (int u = 0; u < 3; ++u) {
    unsigned short* dA = &Asl[u][w * 512];
    unsigned short* dB = &Bsl[u][w * 512];
    gload_lds16(srcA0 + u * BK2, dA);
    gload_lds16(srcA1 + u * BK2, dA + 4096);
    gload_lds16(srcB0 + u * BK2, dB);
    gload_lds16(srcB1 + u * BK2, dB + 4096);
  }

  // ---- main loop: ONE barrier per K-tile ----
  for (int t = 0; t < NKT2; ++t) {
    // counted vmcnt: drain own tile-t loads; keep t+1,t+2 (and later t+3) flying
    if (t < NKT2 - 2)       asm volatile("s_waitcnt vmcnt(8)" ::: "memory");
    else if (t == NKT2 - 2) asm volatile("s_waitcnt vmcnt(4)" ::: "memory");
    else                    asm volatile("s_waitcnt vmcnt(0)" ::: "memory");
    __builtin_amdgcn_s_barrier();   // tile t resident; t-1 reads all consumed

    const int tp = t + 3;
    if (tp < NKT2) {                // stage tile t+3 into slot (t+3)&3
      unsigned short* dA = &Asl[tp & 3][w * 512];
      unsigned short* dB = &Bsl[tp & 3][w * 512];
      gload_lds16(srcA0 + tp * BK2, dA);
      gload_lds16(srcA1 + tp * BK2, dA + 4096);
      gload_lds16(srcB0 + tp * BK2, dB);
      gload_lds16(srcB1 + tp * BK2, dB + 4096);
    }
    asm volatile("" ::: "memory");  // keep stage issue ahead of the reads

    const unsigned short* As = Asl[t & 3];
    const unsigned short* Bs = Bsl[t & 3];
    s16x8 af[8], bf[4];
#pragma unroll
    for (int j = 0; j < 8; ++j) af[j] = *(const s16x8*)&As[offA[j]];
#pragma unroll
    for (int n = 0; n < 4; ++n) bf[n] = *(const s16x8*)&Bs[offB[n]];
#pragma unroll
    for (int j = 0; j < 8; ++j)
#pragma unroll
      for (int n = 0; n < 4; ++n)
        acc[j][n] = __builtin_amdgcn_mfma_f32_16x16x32_bf16(af[j], bf[n], acc[j][n], 0, 0, 0);
  }

  // ---- epilogue: e = tanh(acc+bias); l = sum exp(e), c = sum exp(e)*x ----
  // C/D layout: col = lane&15, row = (lane>>4)*4 + reg. tanh bounded -> no
  // max subtraction (exp(e) in [0.37, 2.72]).
  float lsum[4], csum[4];
#pragma unroll
  for (int nr = 0; nr < 4; nr++) {
    const int o = n0 + wn * 64 + nr * 16 + lr;
    const float bv = bias[o];
    float lacc = 0.f, cacc = 0.f;
#pragma unroll
    for (int mr = 0; mr < 8; mr++) {
      const int sr = m0 + wm * 128 + mr * 16 + lk * 4;
#pragma unroll
      for (int r = 0; r < 4; r++) {
        float e  = acc[mr][nr][r] + bv;
        float t  = __expf(2.f * e);
        float th = 1.f - __fdividef(2.f, t + 1.f);  // tanh(e)
        float sc = __expf(th);
        float xv = bf2f(Xb[(size_t)(sr + r) * Kdim + o]);  // L2-warm
        lacc += sc;
        cacc += sc * xv;
      }
    }
    lacc += __shfl_xor(lacc, 16); lacc += __shfl_xor(lacc, 32);
    cacc += __shfl_xor(cacc, 16); cacc += __shfl_xor(cacc, 32);
    lsum[nr] = lacc; csum[nr] = cacc;
  }

  if (lk == 0) {
#pragma unroll
    for (int nr = 0; nr < 4; nr++) {
      red[wm][0][wn * 64 + nr * 16 + lr] = lsum[nr];
      red[wm][1][wn * 64 + nr * 16 + lr] = csum[nr];
    }
  }
  __syncthreads();
  if (tid < BN2) {
    float L = red[0][0][tid] + red[1][0][tid];
    float C = red[0][1][tid] + red[1][1][tid];
    lpart[(size_t)mt * Ndim + n0 + tid] = L;
    cpart[(size_t)mt * Ndim + n0 + tid] = C;
  }
}

// ---- fallback main (R2-proven 128^2 reg-staged path, if ws too small) ----
__global__ __launch_bounds__(256) void attn_main_fb(
    const float* __restrict__ X, const unsigned short* __restrict__ Wb,
    const float* __restrict__ bias, float* __restrict__ lpart, float* __restrict__ cpart) {
  __shared__ unsigned short Al[BM * BK];
  __shared__ unsigned short Bl[BN * BK];
  __shared__ float red[2][2][BN];
  int bid = blockIdx.x;
  int swz = (bid & 7) * (MT * NT / 8) + (bid >> 3);
  int mt = swz >> 3, nt = swz & 7;
  const int m0 = mt * BM, n0 = nt * BN;
  const int tid = threadIdx.x, lane = tid & 63, wave = tid >> 6;
  const int wm = wave >> 1, wn = wave & 1, lr = lane & 15, lk = lane >> 4;
  f32x4 acc[4][4];
#pragma unroll
  for (int i = 0; i < 4; i++)
#pragma unroll
    for (int j = 0; j < 4; j++) acc[i][j] = (f32x4){0.f, 0.f, 0.f, 0.f};
  const int srow_st = tid >> 1, scol_st = (tid & 1) * 16;
  const float*          Ag = X  + (size_t)(m0 + srow_st) * Kdim + scol_st;
  const unsigned short* Bg = Wb + (size_t)(n0 + srow_st) * Kdim + scol_st;
  float4 a0 = *(const float4*)(Ag + 0), a1 = *(const float4*)(Ag + 4);
  float4 a2 = *(const float4*)(Ag + 8), a3 = *(const float4*)(Ag + 12);
  s16x8 b0 = *(const s16x8*)(Bg + 0), b1 = *(const s16x8*)(Bg + 8);
  for (int kt = 0; kt < NKT; ++kt) {
    __syncthreads();
    *(s16x8*)&Al[srow_st * BK + scol_st]     = cvt8(a0, a1);
    *(s16x8*)&Al[srow_st * BK + scol_st + 8] = cvt8(a2, a3);
    *(s16x8*)&Bl[srow_st * BK + scol_st]     = b0;
    *(s16x8*)&Bl[srow_st * BK + scol_st + 8] = b1;
    __syncthreads();
    if (kt + 1 < NKT) {
      const float* ap = Ag + (kt + 1) * BK;
      a0 = *(const float4*)(ap);     a1 = *(const float4*)(ap + 4);
      a2 = *(const float4*)(ap + 8); a3 = *(const float4*)(ap + 12);
      const unsigned short* bp = Bg + (kt + 1) * BK;
      b0 = *(const s16x8*)(bp);      b1 = *(const s16x8*)(bp + 8);
    }
    s16x8 af[4], bfr[4];
#pragma unroll
    for (int mr = 0; mr < 4; mr++)
      af[mr] = *(const s16x8*)&Al[(wm * 64 + mr * 16 + lr) * BK + lk * 8];
#pragma unroll
    for (int nr = 0; nr < 4; nr++)
      bfr[nr] = *(const s16x8*)&Bl[(wn * 64 + nr * 16 + lr) * BK + lk * 8];
#pragma unroll
    for (int mr = 0; mr < 4; mr++)
#pragma unroll
      for (int nr = 0; nr < 4; nr++)
        acc[mr][nr] = __builtin_amdgcn_mfma_f32_16x16x32_bf16(af[mr], bfr[nr], acc[mr][nr], 0, 0, 0);
  }
  float lsum[4], csum[4];
#pragma unroll
  for (int nr = 0; nr < 4; nr++) {
    const int o = n0 + wn * 64 + nr * 16 + lr;
    const float bv = bias[o];
    float lacc = 0.f, cacc = 0.f;
#pragma unroll
    for (int mr = 0; mr < 4; mr++) {
      const int sr = m0 + wm * 64 + mr * 16 + lk * 4;
#pragma unroll
      for (int r = 0; r < 4; r++) {
        float e  = acc[mr][nr][r] + bv;
        float t  = __expf(2.f * e);
        float th = 1.f - __fdividef(2.f, t + 1.f);
        float sc = __expf(th);
        float xv = X[(size_t)(sr + r) * Kdim + o];
        lacc += sc; cacc += sc * xv;
      }
    }
    lacc += __shfl_xor(lacc, 16); lacc += __shfl_xor(lacc, 32);
    cacc += __shfl_xor(cacc, 16); cacc += __shfl_xor(cacc, 32);
    lsum[nr] = lacc; csum[nr] = cacc;
  }
  if (lk == 0) {
#pragma unroll
    for (int nr = 0; nr < 4; nr++) {
      red[wm][0][wn * 64 + nr * 16 + lr] = lsum[nr];
      red[wm][1][wn * 64 + nr * 16 + lr] = csum[nr];
    }
  }
  __syncthreads();
  if (tid < BN) {
    float L = red[0][0][tid] + red[1][0][tid];
    float C = red[0][1][tid] + red[1][1][tid];
    lpart[(size_t)mt * Ndim + n0 + tid] = L;
    cpart[(size_t)mt * Ndim + n0 + tid] = C;
  }
}

// ---- kernel 3: combine s-chunks -> out[b][o] ----
__global__ __launch_bounds__(256) void finalize_kernel(const float* __restrict__ lpart,
                                                       const float* __restrict__ cpart,
                                                       float* __restrict__ out, int chunks) {
  int i = blockIdx.x * 256 + threadIdx.x;
  int b = i >> 10, o = i & 1023;
  float L = 0.f, C = 0.f;
  for (int sc = 0; sc < chunks; ++sc) {
    size_t idx = (size_t)(b * chunks + sc) * Ndim + o;
    L += lpart[idx];
    C += cpart[idx];
  }
  out[i] = C / L;
}

extern "C" void kernel_launch(void* const* d_in, const int* in_sizes, int n_in,
                              void* d_out, int out_size, void* d_ws, size_t ws_size,
                              hipStream_t stream) {
  const float* X    = (const float*)d_in[0];
  const float* W    = (const float*)d_in[1];
  const float* bias = (const float*)d_in[2];
  float* out = (float*)d_out;

  const size_t xb_bytes = (size_t)Mtot * Kdim * 2;        // 134 MB
  const size_t wb_bytes = (size_t)Ndim * Kdim * 2;        // 2 MB
  const size_t lp_bytes = (size_t)MT * Ndim * 4;          // 2 MB (max of both paths)
  const size_t need = xb_bytes + wb_bytes + 2 * lp_bytes;

  if (ws_size >= need) {
    unsigned short* Xb = (unsigned short*)d_ws;
    unsigned short* Wb = (unsigned short*)((char*)d_ws + xb_bytes);
    float* lpart = (float*)((char*)d_ws + xb_bytes + wb_bytes);
    float* cpart = lpart + (size_t)MT2 * Ndim;
    xconv_kernel<<<dim3(Mtot * (Kdim / 8) / 256), dim3(256), 0, stream>>>(X, Xb);
    wconv_kernel<<<dim3(Ndim * Kdim / 1024), dim3(256), 0, stream>>>(W, Wb);
    attn_main<<<dim3(MT2 * NT2), dim3(512), 0, stream>>>(Xb, Wb, bias, lpart, cpart);
    finalize_kernel<<<dim3(Bsz * Hdim / 256), dim3(256), 0, stream>>>(lpart, cpart, out,
                                                                      Sdim / BM2);
  } else {
    unsigned short* Wb = (unsigned short*)d_ws;
    float* lpart = (float*)((char*)d_ws + wb_bytes);
    float* cpart = lpart + (size_t)MT * Ndim;
    wconv_kernel<<<dim3(Ndim * Kdim / 1024), dim3(256), 0, stream>>>(W, Wb);
    attn_main_fb<<<dim3(MT * NT), dim3(256), 0, stream>>>(X, Wb, bias, lpart, cpart);
    finalize_kernel<<<dim3(Bsz * Hdim / 256), dim3(256), 0, stream>>>(lpart, cpart, out,
                                                                      Sdim / BM);
  }
}

// Round 5
// 244.897 us; speedup vs baseline: 1.1449x; 1.1449x over previous
//
#include <hip/hip_runtime.h>
#include <hip/hip_bf16.h>

// Problem: B=16, S=4096, H=1024
//   energy = tanh(x @ W^T + b); scores = softmax(energy, axis=S); out = sum_S scores*x
// GEMM view: M = B*S = 65536, N = H = 1024, K = H = 1024, both operands K-contiguous.
#define Bsz  16
#define Sdim 4096
#define Hdim 1024
#define Mtot (Bsz * Sdim)   // 65536
#define Kdim Hdim
#define Ndim Hdim

// ---- primary tile geometry (256^2, BK=64, 8 waves, 2-slot ring, 8-phase) ----
#define BM2 256
#define BN2 256
#define BK64 64
#define MT2 (Mtot / BM2)    // 256
#define NT2 (Ndim / BN2)    // 4
#define NKT64 (Kdim / BK64) // 16 K-tiles

// ---- fallback geometry (R1/R2-proven 128^2) ----
#define BM 128
#define BN 128
#define BK 32
#define MT (Mtot / BM)      // 512
#define NT (Ndim / BN)      // 8
#define NKT (Kdim / BK)     // 32

typedef short s16x8 __attribute__((ext_vector_type(8)));
typedef float f32x4 __attribute__((ext_vector_type(4)));

__device__ __forceinline__ unsigned short f2bf(float f) {
  __hip_bfloat16 h = __float2bfloat16(f);
  unsigned short u;
  __builtin_memcpy(&u, &h, 2);
  return u;
}
__device__ __forceinline__ float bf2f(unsigned short u) {
  __hip_bfloat16 h;
  __builtin_memcpy(&h, &u, 2);
  return __bfloat162float(h);
}
__device__ __forceinline__ s16x8 cvt8(float4 u, float4 v) {
  s16x8 r;
  r[0] = (short)f2bf(u.x); r[1] = (short)f2bf(u.y);
  r[2] = (short)f2bf(u.z); r[3] = (short)f2bf(u.w);
  r[4] = (short)f2bf(v.x); r[5] = (short)f2bf(v.y);
  r[6] = (short)f2bf(v.z); r[7] = (short)f2bf(v.w);
  return r;
}

// async global->LDS, 16B per lane; LDS dest is wave-uniform base + lane*16
__device__ __forceinline__ void gload_lds16(const unsigned short* g, unsigned short* l) {
  __builtin_amdgcn_global_load_lds(
      (const __attribute__((address_space(1))) unsigned int*)g,
      (__attribute__((address_space(3))) unsigned int*)l,
      16, 0, 0);
}

// ---- kernel 0: X fp32 [M][K] -> bf16 Xb (134 MB) ----
__global__ __launch_bounds__(256) void xconv_kernel(const float* __restrict__ X,
                                                    unsigned short* __restrict__ Xb) {
  size_t i = (size_t)blockIdx.x * 256 + threadIdx.x;  // 8 elements per thread
  float4 u = reinterpret_cast<const float4*>(X)[2 * i];
  float4 v = reinterpret_cast<const float4*>(X)[2 * i + 1];
  reinterpret_cast<s16x8*>(Xb)[i] = cvt8(u, v);
}

// ---- kernel 1: W fp32 [N][K] -> bf16 Wb (2 MB) ----
__global__ __launch_bounds__(256) void wconv_kernel(const float* __restrict__ W,
                                                    unsigned short* __restrict__ Wb) {
  int i = blockIdx.x * 256 + threadIdx.x;
  float4 v = reinterpret_cast<const float4*>(W)[i];
  ushort4 o;
  o.x = f2bf(v.x); o.y = f2bf(v.y); o.z = f2bf(v.z); o.w = f2bf(v.w);
  reinterpret_cast<ushort4*>(Wb)[i] = o;
}

// =====================================================================
// kernel 2 (primary): 256^2, BK=64, m201-style 8-phase schedule.
//
// 512 threads = 8 waves (2 wm x 4 wn); per-wave output 128x64.
// Per K-tile(64): 4 phases (mh,kk) of 16 MFMA each; B-frags register-
// cached across mh phases -> LDS frag reads = 24 b128/wave/K-tile (floor).
// LDS: [slot 2][kk 2][256 rows][32 cols] per operand, slot = K-tile ring;
// each (kk, 128-row chunk) is a contiguous 8 KB gload_lds unit.
// Staging: tile t+1 into slot ~t&1 (never the live slot), one 16 KB
// kh-unit per phase (2 gload_lds/thread): ph1->A-k0, ph2->B-k0,
// ph3->A-k1, ph4->B-k1.
// Counted vmcnt (proved by induction; oldest-first drain):
//   ph1 end: vmcnt(2) -> lands A-k1,B-k1 of tile t (read in ph2/ph4)
//   ph4 end: vmcnt(4) -> lands A-k0,B-k0 of tile t+1 (read in t+1 ph1)
// Raw barriers with no drain before them (bleed); after the mid-phase
// barrier: lgkmcnt(0) + sched_barrier(0) (rule #18), setprio(1) MFMAs.
//
// Swizzle (conflict-free, exact 8-deep uniform): within a [256][32]
// subarray, logical (row, lk 16B-slot) stored at slot lk ^ ((row>>1)&3).
// Inverse applied to the per-lane GLOBAL source column so the linear
// gload_lds dest lands data pre-swizzled: src slot = (l&3) ^ ((l>>3)&3).
// =====================================================================
__global__ __launch_bounds__(512, 2) void attn_main(
    const unsigned short* __restrict__ Xb,  // [Mtot][Kdim] bf16
    const unsigned short* __restrict__ Wb,  // [Ndim][Kdim] bf16
    const float* __restrict__ bias,         // [Ndim]
    float* __restrict__ lpart,              // [MT2][Ndim]
    float* __restrict__ cpart) {            // [MT2][Ndim]
  __shared__ unsigned short Asl[2][2][BM2 * 32];  // [slot][kk][row*32+c] 64 KB
  __shared__ unsigned short Bsl[2][2][BN2 * 32];  // 64 KB
  __shared__ float red[2][2][BN2];                // 4 KB

  // XCD-chunked bijective swizzle (nwg=1024, 1024%8==0)
  int bid = blockIdx.x;
  int swz = (bid & 7) * (MT2 * NT2 / 8) + (bid >> 3);
  const int mt = swz >> 2;         // 0..255
  const int nt = swz & 3;          // 0..3
  const int m0 = mt * BM2;
  const int n0 = nt * BN2;

  const int tid  = threadIdx.x;
  const int l    = tid & 63;       // lane
  const int w    = tid >> 6;       // wave 0..7
  const int wm   = w >> 2;         // 0..1 (M half)
  const int wn   = w & 3;          // 0..3 (N quarter)
  const int lr   = l & 15;
  const int lk   = l >> 4;

  f32x4 acc[8][4];
#pragma unroll
  for (int i = 0; i < 8; i++)
#pragma unroll
    for (int j = 0; j < 4; j++) acc[i][j] = (f32x4){0.f, 0.f, 0.f, 0.f};

  // ---- staging source (inverse-swizzled global addresses) ----
  // gload unit = 512 thr x 16B = 8 KB = 128 rows x 32 cols. Wave w covers
  // rows [w*16, w*16+16); lane row += l>>2, src col slot = (l&3)^((l>>3)&3).
  const int srow = w * 16 + (l >> 2);
  const int scol = (((l & 3) ^ ((l >> 3) & 3)) << 3);  // elements
  const unsigned short* srcA0 = Xb + (size_t)(m0 + srow) * Kdim + scol;
  const unsigned short* srcA1 = srcA0 + (size_t)128 * Kdim;  // rows 128-255
  const unsigned short* srcB0 = Wb + (size_t)(n0 + srow) * Kdim + scol;
  const unsigned short* srcB1 = srcB0 + (size_t)128 * Kdim;

  // ---- fragment read offsets (swizzled, elements within a [256][32] kk-subarray) ----
  int offA[2][4], offB[4];
#pragma unroll
  for (int mh = 0; mh < 2; mh++)
#pragma unroll
    for (int j = 0; j < 4; j++) {
      const int r = wm * 128 + mh * 64 + j * 16 + lr;
      offA[mh][j] = r * 32 + ((lk ^ ((r >> 1) & 3)) << 3);
    }
#pragma unroll
  for (int n = 0; n < 4; n++) {
    const int rn = wn * 64 + n * 16 + lr;
    offB[n] = rn * 32 + ((lk ^ ((rn >> 1) & 3)) << 3);
  }

  // stage one 16 KB kh-unit (2 gload_lds) of tile tp
#define STAGE_A(tp, kh) do {                                            \
    unsigned short* d = &Asl[(tp) & 1][kh][w * 512];                    \
    const unsigned short* g = srcA0 + (size_t)(tp) * 64 + (kh) * 32;    \
    gload_lds16(g, d);                                                  \
    gload_lds16(g + (size_t)128 * Kdim, d + 4096);                      \
  } while (0)
#define STAGE_B(tp, kh) do {                                            \
    unsigned short* d = &Bsl[(tp) & 1][kh][w * 512];                    \
    const unsigned short* g = srcB0 + (size_t)(tp) * 64 + (kh) * 32;    \
    gload_lds16(g, d);                                                  \
    gload_lds16(g + (size_t)128 * Kdim, d + 4096);                      \
  } while (0)

#define MID_BARRIER() do {                                   \
    asm volatile("" ::: "memory");                           \
    __builtin_amdgcn_s_barrier();                            \
    asm volatile("s_waitcnt lgkmcnt(0)" ::: "memory");       \
    __builtin_amdgcn_sched_barrier(0);                       \
  } while (0)
#define END_BARRIER() do {                                   \
    asm volatile("" ::: "memory");                           \
    __builtin_amdgcn_s_barrier();                            \
  } while (0)

  // ---- prologue: stage tile 0 fully (A-k0, B-k0 first), land A-k0/B-k0 ----
  STAGE_A(0, 0); STAGE_B(0, 0); STAGE_A(0, 1); STAGE_B(0, 1);
  asm volatile("s_waitcnt vmcnt(4)" ::: "memory");  // A-k0,B-k0 landed
  END_BARRIER();

  s16x8 bf0[4], bf1[4];

  // ---- main loop: 16 K-tiles x 4 phases ----
  for (int t = 0; t < NKT64; ++t) {
    const int s = t & 1;
    const unsigned short* As0 = Asl[s][0];
    const unsigned short* As1 = Asl[s][1];
    const unsigned short* Bs0 = Bsl[s][0];
    const unsigned short* Bs1 = Bsl[s][1];
    const int tp = t + 1;
    const bool more = (tp < NKT64);
    s16x8 af[4];

    // ===== phase 1: (mh0, kk0) — reads A(mh0,k0)+B(k0); stage A-k0(t+1) =====
#pragma unroll
    for (int j = 0; j < 4; ++j) af[j] = *(const s16x8*)&As0[offA[0][j]];
#pragma unroll
    for (int n = 0; n < 4; ++n) bf0[n] = *(const s16x8*)&Bs0[offB[n]];
    if (more) STAGE_A(tp, 0);
    MID_BARRIER();
    __builtin_amdgcn_s_setprio(1);
#pragma unroll
    for (int j = 0; j < 4; ++j)
#pragma unroll
      for (int n = 0; n < 4; ++n)
        acc[j][n] = __builtin_amdgcn_mfma_f32_16x16x32_bf16(af[j], bf0[n], acc[j][n], 0, 0, 0);
    __builtin_amdgcn_s_setprio(0);
    if (more) asm volatile("s_waitcnt vmcnt(2)" ::: "memory");  // lands A-k1,B-k1 of t
    else      asm volatile("s_waitcnt vmcnt(0)" ::: "memory");
    END_BARRIER();

    // ===== phase 2: (mh0, kk1) — reads A(mh0,k1)+B(k1); stage B-k0(t+1) =====
#pragma unroll
    for (int j = 0; j < 4; ++j) af[j] = *(const s16x8*)&As1[offA[0][j]];
#pragma unroll
    for (int n = 0; n < 4; ++n) bf1[n] = *(const s16x8*)&Bs1[offB[n]];
    if (more) STAGE_B(tp, 0);
    MID_BARRIER();
    __builtin_amdgcn_s_setprio(1);
#pragma unroll
    for (int j = 0; j < 4; ++j)
#pragma unroll
      for (int n = 0; n < 4; ++n)
        acc[j][n] = __builtin_amdgcn_mfma_f32_16x16x32_bf16(af[j], bf1[n], acc[j][n], 0, 0, 0);
    __builtin_amdgcn_s_setprio(0);
    END_BARRIER();

    // ===== phase 3: (mh1, kk0) — reads A(mh1,k0); B(k0) cached; stage A-k1(t+1) =====
#pragma unroll
    for (int j = 0; j < 4; ++j) af[j] = *(const s16x8*)&As0[offA[1][j]];
    if (more) STAGE_A(tp, 1);
    MID_BARRIER();
    __builtin_amdgcn_s_setprio(1);
#pragma unroll
    for (int j = 0; j < 4; ++j)
#pragma unroll
      for (int n = 0; n < 4; ++n)
        acc[4 + j][n] = __builtin_amdgcn_mfma_f32_16x16x32_bf16(af[j], bf0[n], acc[4 + j][n], 0, 0, 0);
    __builtin_amdgcn_s_setprio(0);
    END_BARRIER();

    // ===== phase 4: (mh1, kk1) — reads A(mh1,k1); B(k1) cached; stage B-k1(t+1) =====
#pragma unroll
    for (int j = 0; j < 4; ++j) af[j] = *(const s16x8*)&As1[offA[1][j]];
    if (more) STAGE_B(tp, 1);
    MID_BARRIER();
    __builtin_amdgcn_s_setprio(1);
#pragma unroll
    for (int j = 0; j < 4; ++j)
#pragma unroll
      for (int n = 0; n < 4; ++n)
        acc[4 + j][n] = __builtin_amdgcn_mfma_f32_16x16x32_bf16(af[j], bf1[n], acc[4 + j][n], 0, 0, 0);
    __builtin_amdgcn_s_setprio(0);
    if (more) asm volatile("s_waitcnt vmcnt(4)" ::: "memory");  // lands A-k0,B-k0 of t+1
    END_BARRIER();
  }

  // ---- epilogue: e = tanh(acc+bias); l = sum exp(e), c = sum exp(e)*x ----
  // C/D layout: col = lane&15, row = (lane>>4)*4 + reg.
  // acc[m8] rows: wm*128 + (m8>>2)*64 + (m8&3)*16. tanh bounded -> no max sub.
  float lsum[4], csum[4];
#pragma unroll
  for (int nr = 0; nr < 4; nr++) {
    const int o = n0 + wn * 64 + nr * 16 + lr;
    const float bv = bias[o];
    float lacc = 0.f, cacc = 0.f;
#pragma unroll
    for (int m8 = 0; m8 < 8; m8++) {
      const int sr = m0 + wm * 128 + (m8 >> 2) * 64 + (m8 & 3) * 16 + lk * 4;
#pragma unroll
      for (int r = 0; r < 4; r++) {
        float e  = acc[m8][nr][r] + bv;
        float t  = __expf(2.f * e);
        float th = 1.f - __fdividef(2.f, t + 1.f);  // tanh(e)
        float sc = __expf(th);
        float xv = bf2f(Xb[(size_t)(sr + r) * Kdim + o]);  // L2-warm
        lacc += sc;
        cacc += sc * xv;
      }
    }
    lacc += __shfl_xor(lacc, 16); lacc += __shfl_xor(lacc, 32);
    cacc += __shfl_xor(cacc, 16); cacc += __shfl_xor(cacc, 32);
    lsum[nr] = lacc; csum[nr] = cacc;
  }

  if (lk == 0) {
#pragma unroll
    for (int nr = 0; nr < 4; nr++) {
      red[wm][0][wn * 64 + nr * 16 + lr] = lsum[nr];
      red[wm][1][wn * 64 + nr * 16 + lr] = csum[nr];
    }
  }
  __syncthreads();
  if (tid < BN2) {
    float L = red[0][0][tid] + red[1][0][tid];
    float C = red[0][1][tid] + red[1][1][tid];
    lpart[(size_t)mt * Ndim + n0 + tid] = L;
    cpart[(size_t)mt * Ndim + n0 + tid] = C;
  }
}

// ---- fallback main (R2-proven 128^2 reg-staged path, if ws too small) ----
__global__ __launch_bounds__(256) void attn_main_fb(
    const float* __restrict__ X, const unsigned short* __restrict__ Wb,
    const float* __restrict__ bias, float* __restrict__ lpart, float* __restrict__ cpart) {
  __shared__ unsigned short Al[BM * BK];
  __shared__ unsigned short Bl[BN * BK];
  __shared__ float red[2][2][BN];
  int bid = blockIdx.x;
  int swz = (bid & 7) * (MT * NT / 8) + (bid >> 3);
  int mt = swz >> 3, nt = swz & 7;
  const int m0 = mt * BM, n0 = nt * BN;
  const int tid = threadIdx.x, lane = tid & 63, wave = tid >> 6;
  const int wm = wave >> 1, wn = wave & 1, lr = lane & 15, lk = lane >> 4;
  f32x4 acc[4][4];
#pragma unroll
  for (int i = 0; i < 4; i++)
#pragma unroll
    for (int j = 0; j < 4; j++) acc[i][j] = (f32x4){0.f, 0.f, 0.f, 0.f};
  const int srow_st = tid >> 1, scol_st = (tid & 1) * 16;
  const float*          Ag = X  + (size_t)(m0 + srow_st) * Kdim + scol_st;
  const unsigned short* Bg = Wb + (size_t)(n0 + srow_st) * Kdim + scol_st;
  float4 a0 = *(const float4*)(Ag + 0), a1 = *(const float4*)(Ag + 4);
  float4 a2 = *(const float4*)(Ag + 8), a3 = *(const float4*)(Ag + 12);
  s16x8 b0 = *(const s16x8*)(Bg + 0), b1 = *(const s16x8*)(Bg + 8);
  for (int kt = 0; kt < NKT; ++kt) {
    __syncthreads();
    *(s16x8*)&Al[srow_st * BK + scol_st]     = cvt8(a0, a1);
    *(s16x8*)&Al[srow_st * BK + scol_st + 8] = cvt8(a2, a3);
    *(s16x8*)&Bl[srow_st * BK + scol_st]     = b0;
    *(s16x8*)&Bl[srow_st * BK + scol_st + 8] = b1;
    __syncthreads();
    if (kt + 1 < NKT) {
      const float* ap = Ag + (kt + 1) * BK;
      a0 = *(const float4*)(ap);     a1 = *(const float4*)(ap + 4);
      a2 = *(const float4*)(ap + 8); a3 = *(const float4*)(ap + 12);
      const unsigned short* bp = Bg + (kt + 1) * BK;
      b0 = *(const s16x8*)(bp);      b1 = *(const s16x8*)(bp + 8);
    }
    s16x8 af[4], bfr[4];
#pragma unroll
    for (int mr = 0; mr < 4; mr++)
      af[mr] = *(const s16x8*)&Al[(wm * 64 + mr * 16 + lr) * BK + lk * 8];
#pragma unroll
    for (int nr = 0; nr < 4; nr++)
      bfr[nr] = *(const s16x8*)&Bl[(wn * 64 + nr * 16 + lr) * BK + lk * 8];
#pragma unroll
    for (int mr = 0; mr < 4; mr++)
#pragma unroll
      for (int nr = 0; nr < 4; nr++)
        acc[mr][nr] = __builtin_amdgcn_mfma_f32_16x16x32_bf16(af[mr], bfr[nr], acc[mr][nr], 0, 0, 0);
  }
  float lsum[4], csum[4];
#pragma unroll
  for (int nr = 0; nr < 4; nr++) {
    const int o = n0 + wn * 64 + nr * 16 + lr;
    const float bv = bias[o];
    float lacc = 0.f, cacc = 0.f;
#pragma unroll
    for (int mr = 0; mr < 4; mr++) {
      const int sr = m0 + wm * 64 + mr * 16 + lk * 4;
#pragma unroll
      for (int r = 0; r < 4; r++) {
        float e  = acc[mr][nr][r] + bv;
        float t  = __expf(2.f * e);
        float th = 1.f - __fdividef(2.f, t + 1.f);
        float sc = __expf(th);
        float xv = X[(size_t)(sr + r) * Kdim + o];
        lacc += sc; cacc += sc * xv;
      }
    }
    lacc += __shfl_xor(lacc, 16); lacc += __shfl_xor(lacc, 32);
    cacc += __shfl_xor(cacc, 16); cacc += __shfl_xor(cacc, 32);
    lsum[nr] = lacc; csum[nr] = cacc;
  }
  if (lk == 0) {
#pragma unroll
    for (int nr = 0; nr < 4; nr++) {
      red[wm][0][wn * 64 + nr * 16 + lr] = lsum[nr];
      red[wm][1][wn * 64 + nr * 16 + lr] = csum[nr];
    }
  }
  __syncthreads();
  if (tid < BN) {
    float L = red[0][0][tid] + red[1][0][tid];
    float C = red[0][1][tid] + red[1][1][tid];
    lpart[(size_t)mt * Ndim + n0 + tid] = L;
    cpart[(size_t)mt * Ndim + n0 + tid] = C;
  }
}

// ---- kernel 3: combine s-chunks -> out[b][o] ----
__global__ __launch_bounds__(256) void finalize_kernel(const float* __restrict__ lpart,
                                                       const float* __restrict__ cpart,
                                                       float* __restrict__ out, int chunks) {
  int i = blockIdx.x * 256 + threadIdx.x;
  int b = i >> 10, o = i & 1023;
  float L = 0.f, C = 0.f;
  for (int sc = 0; sc < chunks; ++sc) {
    size_t idx = (size_t)(b * chunks + sc) * Ndim + o;
    L += lpart[idx];
    C += cpart[idx];
  }
  out[i] = C / L;
}

extern "C" void kernel_launch(void* const* d_in, const int* in_sizes, int n_in,
                              void* d_out, int out_size, void* d_ws, size_t ws_size,
                              hipStream_t stream) {
  const float* X    = (const float*)d_in[0];
  const float* W    = (const float*)d_in[1];
  const float* bias = (const float*)d_in[2];
  float* out = (float*)d_out;

  const size_t xb_bytes = (size_t)Mtot * Kdim * 2;        // 134 MB
  const size_t wb_bytes = (size_t)Ndim * Kdim * 2;        // 2 MB
  const size_t lp_bytes = (size_t)MT * Ndim * 4;          // 2 MB (max of both paths)
  const size_t need = xb_bytes + wb_bytes + 2 * lp_bytes;

  if (ws_size >= need) {
    unsigned short* Xb = (unsigned short*)d_ws;
    unsigned short* Wb = (unsigned short*)((char*)d_ws + xb_bytes);
    float* lpart = (float*)((char*)d_ws + xb_bytes + wb_bytes);
    float* cpart = lpart + (size_t)MT2 * Ndim;
    xconv_kernel<<<dim3(Mtot * (Kdim / 8) / 256), dim3(256), 0, stream>>>(X, Xb);
    wconv_kernel<<<dim3(Ndim * Kdim / 1024), dim3(256), 0, stream>>>(W, Wb);
    attn_main<<<dim3(MT2 * NT2), dim3(512), 0, stream>>>(Xb, Wb, bias, lpart, cpart);
    finalize_kernel<<<dim3(Bsz * Hdim / 256), dim3(256), 0, stream>>>(lpart, cpart, out,
                                                                      Sdim / BM2);
  } else {
    unsigned short* Wb = (unsigned short*)d_ws;
    float* lpart = (float*)((char*)d_ws + wb_bytes);
    float* cpart = lpart + (size_t)MT * Ndim;
    wconv_kernel<<<dim3(Ndim * Kdim / 1024), dim3(256), 0, stream>>>(W, Wb);
    attn_main_fb<<<dim3(MT * NT), dim3(256), 0, stream>>>(X, Wb, bias, lpart, cpart);
    finalize_kernel<<<dim3(Bsz * Hdim / 256), dim3(256), 0, stream>>>(lpart, cpart, out,
                                                                      Sdim / BM);
  }
}